// Round 9
// baseline (122.582 us; speedup 1.0000x reference)
//
#include <hip/hip_runtime.h>
#include <math.h>

#define BB 32
#define LL 128
#define HH 512
#define MM 512
#define NM 544          // 32 x-matrices + 512 centroids
#define EPSF 1e-8f
#define CPLEN 10240     // 10 upper 32x32 tiles * 1024 floats (offdiag pre-scaled by sqrt2)
#define NCH 40          // k-chunks of 256 floats
#define R2C 1.41421356237309505f

typedef __attribute__((ext_vector_type(8))) short short8b;   // 8 bf16
typedef __attribute__((ext_vector_type(4))) float f32x4;
typedef __attribute__((ext_vector_type(16))) float f32x16;

// ---------------- ws layout (floats) ----------------
//   Cp     [544][10240]   @ 0         (Cx centered by K1b; Cy raw)
//   part   [40][32][512]  @ 5570560
//   normsq [544]          @ 6225920   (centered-norm^2 via closed form)
//   hsic   [32][512]      @ 6226464
//   ids    [32] (int)     @ 6242848
//   u      [544][128]     @ 6242880   (raw Gram row sums)
#define NWS_CP    0
#define NWS_PART  5570560
#define NWS_NSQ   6225920
#define NWS_HSIC  6226464
#define NWS_IDS   6242848
#define NWS_U     6242880

__device__ __forceinline__ unsigned pack2(unsigned lo, unsigned hi) {
    return (lo >> 16) | (hi & 0xffff0000u);
}

// exact 3-plane bf16 split of 8 floats (c = p0+p1+p2 to ~2^-24 rel)
__device__ __forceinline__ void split3(const float4 lo, const float4 hi,
                                       uint4& p0, uint4& p1, uint4& p2) {
    float c[8] = {lo.x, lo.y, lo.z, lo.w, hi.x, hi.y, hi.z, hi.w};
    unsigned h[8], m[8], l[8];
#pragma unroll
    for (int i = 0; i < 8; ++i) {
        h[i] = __float_as_uint(c[i]) & 0xffff0000u;
        const float r1 = c[i] - __uint_as_float(h[i]);
        m[i] = __float_as_uint(r1) & 0xffff0000u;
        l[i] = __float_as_uint(r1 - __uint_as_float(m[i]));
    }
    p0 = make_uint4(pack2(h[0],h[1]), pack2(h[2],h[3]), pack2(h[4],h[5]), pack2(h[6],h[7]));
    p1 = make_uint4(pack2(m[0],m[1]), pack2(m[2],m[3]), pack2(m[4],m[5]), pack2(m[6],m[7]));
    p2 = make_uint4(pack2(l[0],l[1]), pack2(l[2],l[3]), pack2(l[4],l[5]), pack2(l[6],l[7]));
}

// 6 significant plane-products: hh, hm, mh, mm, hl, lh
__device__ __forceinline__ void mfma6(f32x16& d, const short8b a[3], const short8b b[3]) {
    d = __builtin_amdgcn_mfma_f32_32x32x16_bf16(a[0], b[0], d, 0, 0, 0);
    d = __builtin_amdgcn_mfma_f32_32x32x16_bf16(a[0], b[1], d, 0, 0, 0);
    d = __builtin_amdgcn_mfma_f32_32x32x16_bf16(a[1], b[0], d, 0, 0, 0);
    d = __builtin_amdgcn_mfma_f32_32x32x16_bf16(a[1], b[1], d, 0, 0, 0);
    d = __builtin_amdgcn_mfma_f32_32x32x16_bf16(a[0], b[2], d, 0, 0, 0);
    d = __builtin_amdgcn_mfma_f32_32x32x16_bf16(a[2], b[0], d, 0, 0, 0);
}

// upper-tile slot for i<=j
__device__ __forceinline__ constexpr int Tix(int i, int j) {
    return i * (7 - i) / 2 + j;
}

// row sums (-> strip i) and, for offdiag, col sums (-> strip j) of raw tile
// (validated in R5: 32x32 C/D layout col=lane&31, row=(q&3)+8*(q>>2)+4*(lane>>5))
__device__ __forceinline__ void tile_sums(f32x16 a, float* S, int i, int j,
                                          bool offd, int lane) {
    const int hi = lane >> 5;
    float rs[16];
#pragma unroll
    for (int q = 0; q < 16; ++q) {
        float s = a[q];
        s += __shfl_xor(s, 1, 64);
        s += __shfl_xor(s, 2, 64);
        s += __shfl_xor(s, 4, 64);
        s += __shfl_xor(s, 8, 64);
        s += __shfl_xor(s, 16, 64);
        rs[q] = s;
    }
    if ((lane & 31) == 0) {
#pragma unroll
        for (int q = 0; q < 16; ++q)
            S[i * 32 + (q & 3) + 8 * (q >> 2) + 4 * hi] += rs[q];
    }
    if (offd) {
        float cs = 0.f;
#pragma unroll
        for (int q = 0; q < 16; ++q) cs += a[q];
        cs += __shfl_xor(cs, 32, 64);
        if (lane < 32) S[j * 32 + lane] += cs;
    }
}

// store raw tile sqrt2-scaled (offdiag); returns ||stored||^2 partial
__device__ __forceinline__ float tile_store(const f32x16& a, float* dst,
                                            bool offd, int lane) {
    const int oct = lane >> 5, col = lane & 31;
    const float sc = offd ? R2C : 1.f;
    float nsq = 0.f;
#pragma unroll
    for (int c = 0; c < 4; ++c) {
        f32x4 o;
#pragma unroll
        for (int q = 0; q < 4; ++q) {
            const float v = a[c * 4 + q] * sc;
            nsq = fmaf(v, v, nsq);
            o[q] = v;
        }
        *(f32x4*)(dst + (c * 2 + oct) * 128 + col * 4) = o;
    }
    return nsq;
}

// =====================================================================
// Per-wave worker: NS strips (global ids S0..), NT tiles (local frag
// index pairs (A,B)). Loads fragments DIRECTLY from global in MFMA
// layout; no LDS, no barriers; depth-1 register double-buffer.
// =====================================================================
template<int NS, int NT, int S0, int S1, int S2, int S3,
         int A0, int B0, int A1, int B1, int A2, int B2>
__device__ __forceinline__ float wave_gram(const float* __restrict__ Amat,
                                           float* __restrict__ Sslice,
                                           float* __restrict__ dstn,
                                           int lane)
{
    const int r31 = lane & 31, oct = lane >> 5;
    const int SS[4] = {S0, S1, S2, S3};

    Sslice[lane] = 0.f;          // wave-private slice, no barrier needed
    Sslice[lane + 64] = 0.f;

    const float* base[4];
#pragma unroll
    for (int s = 0; s < NS; ++s)
        base[s] = Amat + (size_t)(SS[s] * 32 + r31) * HH + oct * 8;

    f32x16 t0, t1, t2;
#pragma unroll
    for (int q = 0; q < 16; ++q) { t0[q] = 0.f; t1[q] = 0.f; t2[q] = 0.f; }

    float4 cur[4][2], nxt[4][2];
#pragma unroll
    for (int s = 0; s < NS; ++s) {
        cur[s][0] = *(const float4*)(base[s]);
        cur[s][1] = *(const float4*)(base[s] + 4);
    }

#pragma unroll 1
    for (int tt = 0; tt < 16; ++tt) {
        // prefetch odd k16 step
#pragma unroll
        for (int s = 0; s < NS; ++s) {
            const float* p = base[s] + (2 * tt + 1) * 16;
            nxt[s][0] = *(const float4*)p;
            nxt[s][1] = *(const float4*)(p + 4);
        }
        {   // compute even step from cur
            short8b fr[4][3];
#pragma unroll
            for (int s = 0; s < NS; ++s) {
                uint4 u0, u1, u2;
                split3(cur[s][0], cur[s][1], u0, u1, u2);
                fr[s][0] = *(short8b*)&u0;
                fr[s][1] = *(short8b*)&u1;
                fr[s][2] = *(short8b*)&u2;
            }
            mfma6(t0, fr[A0], fr[B0]);
            if (NT > 1) mfma6(t1, fr[A1], fr[B1]);
            if (NT > 2) mfma6(t2, fr[A2], fr[B2]);
        }
        if (tt < 15) {   // prefetch next even step
#pragma unroll
            for (int s = 0; s < NS; ++s) {
                const float* p = base[s] + (2 * tt + 2) * 16;
                cur[s][0] = *(const float4*)p;
                cur[s][1] = *(const float4*)(p + 4);
            }
        }
        {   // compute odd step from nxt
            short8b fr[4][3];
#pragma unroll
            for (int s = 0; s < NS; ++s) {
                uint4 u0, u1, u2;
                split3(nxt[s][0], nxt[s][1], u0, u1, u2);
                fr[s][0] = *(short8b*)&u0;
                fr[s][1] = *(short8b*)&u1;
                fr[s][2] = *(short8b*)&u2;
            }
            mfma6(t0, fr[A0], fr[B0]);
            if (NT > 1) mfma6(t1, fr[A1], fr[B1]);
            if (NT > 2) mfma6(t2, fr[A2], fr[B2]);
        }
    }

    // raw row/col sums for centering / norm formula
    tile_sums(t0, Sslice, SS[A0], SS[B0], SS[A0] != SS[B0], lane);
    if (NT > 1) tile_sums(t1, Sslice, SS[A1], SS[B1], SS[A1] != SS[B1], lane);
    if (NT > 2) tile_sums(t2, Sslice, SS[A2], SS[B2], SS[A2] != SS[B2], lane);

    // store raw sqrt2-scaled tiles + ||G||^2 partial
    float nsq = tile_store(t0, dstn + Tix(SS[A0], SS[B0]) * 1024,
                           SS[A0] != SS[B0], lane);
    if (NT > 1) nsq += tile_store(t1, dstn + Tix(SS[A1], SS[B1]) * 1024,
                                  SS[A1] != SS[B1], lane);
    if (NT > 2) nsq += tile_store(t2, dstn + Tix(SS[A2], SS[B2]) * 1024,
                                  SS[A2] != SS[B2], lane);
    return nsq;
}

// =====================================================================
// K1: raw Gram, direct-from-global fragments. 544 blocks x 256 threads.
// Stores raw upper tiles (sqrt2-scaled offdiag), row sums u, and the
// CENTERED norm^2 via ||HGH||^2 = ||G||^2 - (2/n)||u||^2 + s^2/n^2.
// =====================================================================
__global__ __launch_bounds__(256, 2)
void gram_direct(const float* __restrict__ x,
                 const float* __restrict__ cent,
                 float* __restrict__ Cp,
                 float* __restrict__ normsq,
                 float* __restrict__ uws)
{
    __shared__ float Ssh[4][128];
    __shared__ float red[256];
    __shared__ float sS, sUsq;

    const int tid = threadIdx.x, lane = tid & 63, wid = tid >> 6;
    const int n = blockIdx.x;
    const float* Amat = (n < BB) ? (x + (size_t)n * LL * HH)
                                 : (cent + (size_t)(n - BB) * LL * HH);
    float* dstn = Cp + (size_t)n * CPLEN;

    float nsq;
    if (wid == 0)      nsq = wave_gram<4,3, 0,1,2,3, 0,3, 1,3, 2,3>(Amat, Ssh[0], dstn, lane);
    else if (wid == 1) nsq = wave_gram<4,3, 3,2,0,1, 0,0, 2,1, 3,1>(Amat, Ssh[1], dstn, lane);
    else if (wid == 2) nsq = wave_gram<3,2, 2,0,1,0, 0,0, 1,2, 0,0>(Amat, Ssh[2], dstn, lane);
    else               nsq = wave_gram<2,2, 0,1,0,0, 0,0, 1,1, 0,0>(Amat, Ssh[3], dstn, lane);
    __syncthreads();

    float u = 0.f;
    if (tid < 128) {
        u = Ssh[0][tid] + Ssh[1][tid] + Ssh[2][tid] + Ssh[3][tid];
        uws[(size_t)n * 128 + tid] = u;
    }
    // s = sum(u)
    red[tid] = (tid < 128) ? u : 0.f;
    __syncthreads();
    for (int s2 = 128; s2 > 0; s2 >>= 1) {
        if (tid < s2) red[tid] += red[tid + s2];
        __syncthreads();
    }
    if (tid == 0) sS = red[0];
    __syncthreads();
    // ||u||^2
    red[tid] = (tid < 128) ? u * u : 0.f;
    __syncthreads();
    for (int s2 = 128; s2 > 0; s2 >>= 1) {
        if (tid < s2) red[tid] += red[tid + s2];
        __syncthreads();
    }
    if (tid == 0) sUsq = red[0];
    __syncthreads();
    // ||G||^2 (stored, sqrt2-weighted == full-matrix norm)
    red[tid] = nsq;
    __syncthreads();
    for (int s2 = 128; s2 > 0; s2 >>= 1) {
        if (tid < s2) red[tid] += red[tid + s2];
        __syncthreads();
    }
    if (tid == 0) {
        const float sv = sS * (1.f / 128.f);
        normsq[n] = red[0] - sUsq * (1.f / 64.f) + sv * sv;
    }
}

// =====================================================================
// K1b: center the 32 Cx matrices in place (stored -= sc*(r_i + r_j - gm)).
// =====================================================================
__global__ __launch_bounds__(256)
void center_x(float* __restrict__ Cp, const float* __restrict__ uws)
{
    __shared__ float rmv[128];
    __shared__ float red[128];
    __shared__ float gmsh;

    const int n = blockIdx.x, tid = threadIdx.x;
    if (tid < 128) {
        const float u = uws[(size_t)n * 128 + tid];
        rmv[tid] = u * (1.f / 128.f);
        red[tid] = u;
    }
    __syncthreads();
    for (int s2 = 64; s2 > 0; s2 >>= 1) {
        if (tid < s2) red[tid] += red[tid + s2];
        __syncthreads();
    }
    if (tid == 0) gmsh = red[0] * (1.f / 16384.f);
    __syncthreads();
    const float gm = gmsh;

    float* base = Cp + (size_t)n * CPLEN;
    static const int TI[10] = {0,0,0,0,1,1,1,2,2,3};
    static const int TJ[10] = {0,1,2,3,1,2,3,2,3,3};
#pragma unroll
    for (int it = 0; it < 10; ++it) {
        const int u4  = it * 256 + tid;       // f32x4 unit, slot == it
        const int rem = u4 & 255;
        const int c2  = rem >> 5;
        const int col = rem & 31;
        const int ab  = (c2 >> 1) * 8 + (c2 & 1) * 4;
        const int i = TI[it], j = TJ[it];
        const float sc = (i == j) ? 1.f : R2C;
        const float cj = rmv[j * 32 + col];
        f32x4 v = *(f32x4*)(base + (size_t)u4 * 4);
#pragma unroll
        for (int q = 0; q < 4; ++q)
            v[q] -= sc * (rmv[i * 32 + ab + q] + cj - gm);
        *(f32x4*)(base + (size_t)u4 * 4) = v;
    }
}

// =====================================================================
// K2: hsic partials. grid = 16 m-tiles x 40 k-chunks (640 blocks).
// =====================================================================
__global__ __launch_bounds__(256, 2)
void hsic_partial(const float* __restrict__ Cp, float* __restrict__ part)
{
    __shared__ float cx[32][260];
    __shared__ float red2[256][16];

    const int tid = threadIdx.x;
    const int bx  = blockIdx.x;
    const int mt  = bx / NCH;
    const int kc  = bx % NCH;
    const int k0  = kc * 256;

#pragma unroll
    for (int i = 0; i < 8; ++i) {
        const int idx = i * 1024 + tid * 4;
        const int b = idx >> 8, k = idx & 255;
        *(float4*)&cx[b][k] = *(const float4*)&Cp[(size_t)b * CPLEN + k0 + k];
    }
    __syncthreads();

    const int kq = tid >> 6;
    const int bg = (tid >> 3) & 7;
    const int mg = tid & 7;
    const float* cyBase = Cp + (size_t)(BB + mt * 32 + mg * 4) * CPLEN + k0 + kq * 64;

    float a[4][4];
#pragma unroll
    for (int bi = 0; bi < 4; ++bi)
#pragma unroll
        for (int mi = 0; mi < 4; ++mi) a[bi][mi] = 0.f;

    for (int kk = 0; kk < 16; ++kk) {
        float4 cy[4];
#pragma unroll
        for (int mi = 0; mi < 4; ++mi)
            cy[mi] = *(const float4*)(cyBase + (size_t)mi * CPLEN + kk * 4);
        float4 cxv[4];
#pragma unroll
        for (int bi = 0; bi < 4; ++bi)
            cxv[bi] = *(const float4*)&cx[bg + bi * 8][kq * 64 + kk * 4];
#pragma unroll
        for (int bi = 0; bi < 4; ++bi)
#pragma unroll
            for (int mi = 0; mi < 4; ++mi) {
                a[bi][mi] = fmaf(cxv[bi].x, cy[mi].x, a[bi][mi]);
                a[bi][mi] = fmaf(cxv[bi].y, cy[mi].y, a[bi][mi]);
                a[bi][mi] = fmaf(cxv[bi].z, cy[mi].z, a[bi][mi]);
                a[bi][mi] = fmaf(cxv[bi].w, cy[mi].w, a[bi][mi]);
            }
    }

#pragma unroll
    for (int e = 0; e < 16; ++e) red2[tid][e] = a[e >> 2][e & 3];
    __syncthreads();
    if (tid < 64) {
#pragma unroll
        for (int e = 0; e < 16; ++e) {
            const float s = red2[tid][e] + red2[tid + 64][e] +
                            red2[tid + 128][e] + red2[tid + 192][e];
            const int bi = e >> 2, mi = e & 3;
            const int b = ((tid >> 3) & 7) + bi * 8;
            const int m = mt * 32 + (tid & 7) * 4 + mi;
            part[((size_t)kc * 32 + b) * 512 + m] = s;
        }
    }
}

// =====================================================================
// K3: combine partials, loss matrix + per-row argmax (first occurrence)
// =====================================================================
__global__ __launch_bounds__(256)
void combine_loss(const float* __restrict__ part,
                  const float* __restrict__ normsq,
                  float* __restrict__ hsic,
                  int* __restrict__ ids,
                  float* __restrict__ out)
{
    __shared__ float rv[256];
    __shared__ int   ri[256];
    const int b = blockIdx.x;
    const int tid = threadIdx.x;
    const float vx = sqrtf(normsq[b]);

    float best = -INFINITY; int bm = 0;
    for (int m = tid; m < MM; m += 256) {
        float s = 0.f;
        for (int kc = 0; kc < NCH; ++kc)
            s += part[((size_t)kc * 32 + b) * 512 + m];
        hsic[b * MM + m] = s;
        const float vy = sqrtf(normsq[BB + m]);
        const float loss = -logf(fabsf(s) / (vx * vy) + EPSF);
        out[1 + b * MM + m] = loss;
        if (loss > best) { best = loss; bm = m; }   // ascending m keeps earliest
    }
    rv[tid] = best; ri[tid] = bm;
    __syncthreads();
    for (int s2 = 128; s2 > 0; s2 >>= 1) {
        if (tid < s2) {
            if (rv[tid + s2] > rv[tid] ||
                (rv[tid + s2] == rv[tid] && ri[tid + s2] < ri[tid])) {
                rv[tid] = rv[tid + s2]; ri[tid] = ri[tid + s2];
            }
        }
        __syncthreads();
    }
    if (tid == 0) { ids[b] = ri[0]; out[1 + BB * MM + b] = (float)ri[0]; }
}

// =====================================================================
// K4: scalar loss via gather identity hsic2[b,c] = hsic[b, idx[c]]
// =====================================================================
__global__ __launch_bounds__(1024)
void scalar_loss(const float* __restrict__ hsic,
                 const float* __restrict__ normsq,
                 const int* __restrict__ ids,
                 float* __restrict__ out)
{
    __shared__ float red[1024];
    const int tid = threadIdx.x;
    const int b = tid >> 5, c = tid & 31;
    const int m = ids[c];
    red[tid] = fabsf(hsic[b * MM + m]) /
               (sqrtf(normsq[b]) * sqrtf(normsq[BB + m]));
    __syncthreads();
    for (int s = 512; s > 0; s >>= 1) {
        if (tid < s) red[tid] += red[tid + s];
        __syncthreads();
    }
    if (tid == 0) out[0] = -logf(red[0] * (1.f / 1024.f) + EPSF);
}

// =====================================================================
extern "C" void kernel_launch(void* const* d_in, const int* in_sizes, int n_in,
                              void* d_out, int out_size, void* d_ws, size_t ws_size,
                              hipStream_t stream) {
    const float* x    = (const float*)d_in[0];   // (32,128,512)
    const float* cent = (const float*)d_in[1];   // (512, 128*512)
    float* out = (float*)d_out;
    float* ws  = (float*)d_ws;

    float* Cp     = ws + NWS_CP;
    float* part   = ws + NWS_PART;
    float* normsq = ws + NWS_NSQ;
    float* hsic   = ws + NWS_HSIC;
    int*   ids    = (int*)(ws + NWS_IDS);
    float* uws    = ws + NWS_U;

    gram_direct<<<NM, 256, 0, stream>>>(x, cent, Cp, normsq, uws);
    center_x<<<BB, 256, 0, stream>>>(Cp, uws);
    hsic_partial<<<16 * NCH, 256, 0, stream>>>(Cp, part);
    combine_loss<<<BB, 256, 0, stream>>>(part, normsq, hsic, ids, out);
    scalar_loss<<<1, 1024, 0, stream>>>(hsic, normsq, ids, out);
}

// Round 10
// 117.250 us; speedup vs baseline: 1.0455x; 1.0455x over previous
//
#include <hip/hip_runtime.h>
#include <math.h>

#define BB 32
#define LL 128
#define HH 512
#define MM 512
#define NM 544          // 32 x-matrices + 512 centroids
#define EPSF 1e-8f
#define CPLEN 10240     // 10 upper 32x32 tiles * 1024 floats (offdiag pre-scaled by sqrt2)
#define NCH 40          // k-chunks of 256 floats
#define R2C 1.41421356237309505f

typedef __attribute__((ext_vector_type(8))) short short8b;   // 8 bf16
typedef __attribute__((ext_vector_type(4))) float f32x4;
typedef __attribute__((ext_vector_type(16))) float f32x16;

// ---------------- ws layout (floats) ----------------
//   Cp     [544][10240]   @ 0
//   part   [40][32][512]  @ 5570560
//   normsq [544]          @ 6225920
//   hsic   [32][512]      @ 6226464
//   ids    [32] (int)     @ 6242848
#define NWS_CP    0
#define NWS_PART  5570560
#define NWS_NSQ   6225920
#define NWS_HSIC  6226464
#define NWS_IDS   6242848

__device__ __forceinline__ unsigned pack2(unsigned lo, unsigned hi) {
    return (lo >> 16) | (hi & 0xffff0000u);
}

// exact 3-plane bf16 split of 8 floats (c = p0+p1+p2 to ~2^-24 rel)
__device__ __forceinline__ void split3(const float4 lo, const float4 hi,
                                       uint4& p0, uint4& p1, uint4& p2) {
    float c[8] = {lo.x, lo.y, lo.z, lo.w, hi.x, hi.y, hi.z, hi.w};
    unsigned h[8], m[8], l[8];
#pragma unroll
    for (int i = 0; i < 8; ++i) {
        h[i] = __float_as_uint(c[i]) & 0xffff0000u;
        const float r1 = c[i] - __uint_as_float(h[i]);
        m[i] = __float_as_uint(r1) & 0xffff0000u;
        l[i] = __float_as_uint(r1 - __uint_as_float(m[i]));
    }
    p0 = make_uint4(pack2(h[0],h[1]), pack2(h[2],h[3]), pack2(h[4],h[5]), pack2(h[6],h[7]));
    p1 = make_uint4(pack2(m[0],m[1]), pack2(m[2],m[3]), pack2(m[4],m[5]), pack2(m[6],m[7]));
    p2 = make_uint4(pack2(l[0],l[1]), pack2(l[2],l[3]), pack2(l[4],l[5]), pack2(l[6],l[7]));
}

// 6 significant plane-products: hh, hm, mh, mm, hl, lh
__device__ __forceinline__ void mfma6(f32x16& d, const short8b a[3], const short8b b[3]) {
    d = __builtin_amdgcn_mfma_f32_32x32x16_bf16(a[0], b[0], d, 0, 0, 0);
    d = __builtin_amdgcn_mfma_f32_32x32x16_bf16(a[0], b[1], d, 0, 0, 0);
    d = __builtin_amdgcn_mfma_f32_32x32x16_bf16(a[1], b[0], d, 0, 0, 0);
    d = __builtin_amdgcn_mfma_f32_32x32x16_bf16(a[1], b[1], d, 0, 0, 0);
    d = __builtin_amdgcn_mfma_f32_32x32x16_bf16(a[0], b[2], d, 0, 0, 0);
    d = __builtin_amdgcn_mfma_f32_32x32x16_bf16(a[2], b[0], d, 0, 0, 0);
}

// row sums (-> strip i) and, for offdiag, col sums (-> strip j) of raw tile
// (verified 32x32 C/D layout: col=lane&31, row=(q&3)+8*(q>>2)+4*(lane>>5))
__device__ __forceinline__ void tile_sums(f32x16 a, float* S, int i, int j,
                                          bool offd, int lane) {
    const int hi = lane >> 5;
    float rs[16];
#pragma unroll
    for (int q = 0; q < 16; ++q) {
        float s = a[q];
        s += __shfl_xor(s, 1, 64);
        s += __shfl_xor(s, 2, 64);
        s += __shfl_xor(s, 4, 64);
        s += __shfl_xor(s, 8, 64);
        s += __shfl_xor(s, 16, 64);
        rs[q] = s;
    }
    if ((lane & 31) == 0) {
#pragma unroll
        for (int q = 0; q < 16; ++q)
            S[i * 32 + (q & 3) + 8 * (q >> 2) + 4 * hi] += rs[q];
    }
    if (offd) {
        float cs = 0.f;
#pragma unroll
        for (int q = 0; q < 16; ++q) cs += a[q];
        cs += __shfl_xor(cs, 32, 64);
        if (lane < 32) S[j * 32 + lane] += cs;
    }
}

// center + scale + store one tile; returns ||.||^2 partial
__device__ __forceinline__ float tile_fin(f32x16 a, const float* rmv, float gm,
                                          bool offd, int i, int j,
                                          float* dst, int lane) {
    const int hi = lane >> 5, col = lane & 31;
    const float cj = rmv[j * 32 + col];
    const float sc = offd ? R2C : 1.f;
    float nsq = 0.f;
#pragma unroll
    for (int c = 0; c < 4; ++c) {
        const float4 ri = *(const float4*)&rmv[i * 32 + c * 8 + hi * 4];
        const float riq[4] = {ri.x, ri.y, ri.z, ri.w};
        f32x4 o;
#pragma unroll
        for (int q = 0; q < 4; ++q) {
            float vq = (a[c * 4 + q] + gm - riq[q] - cj) * sc;
            nsq = fmaf(vq, vq, nsq);
            o[q] = vq;
        }
        *(f32x4*)(dst + (c * 2 + hi) * 128 + col * 4) = o;
    }
    return nsq;
}

// read one 8-float f32 fragment from swizzled LDS chunk + split to 3 planes
__device__ __forceinline__ void frag_rd(const float* fbuf, int r, int u,
                                        short8b f[3]) {
    const int sw = (r & 7) << 4;
    const float4 lo = *(const float4*)((const char*)fbuf + (r * 256 + ((u * 16) ^ sw)));
    const float4 hi = *(const float4*)((const char*)fbuf + (r * 256 + (((u + 1) * 16) ^ sw)));
    uint4 p0, p1, p2;
    split3(lo, hi, p0, p1, p2);
    f[0] = *(short8b*)&p0;
    f[1] = *(short8b*)&p1;
    f[2] = *(short8b*)&p2;
}

// one k64-phase of MFMA work for a wave owning NS strips / NT tiles
template<int NS, int NT, int S0, int S1, int S2,
         int A0, int B0, int A1, int B1, int A2, int B2>
__device__ __forceinline__ void mfma_phase(const float* fbuf, int lane,
                                           f32x16& t0, f32x16& t1, f32x16& t2)
{
    const int o = lane >> 5, r31 = lane & 31;
    const int SS[3] = {S0, S1, S2};
#pragma unroll
    for (int t = 0; t < 4; ++t) {
        short8b fr[3][3];
#pragma unroll
        for (int s = 0; s < NS; ++s)
            frag_rd(fbuf, SS[s] * 32 + r31, t * 4 + o * 2, fr[s]);
        mfma6(t0, fr[A0], fr[B0]);
        if (NT > 1) mfma6(t1, fr[A1], fr[B1]);
        if (NT > 2) mfma6(t2, fr[A2], fr[B2]);
    }
}

// =====================================================================
// K1: phase-structured centered Gram. 544 blocks x 256 threads.
// 8 k64-phases: dense 256B-per-row global loads -> swizzled f32 LDS ->
// fragment read + reg split3 -> MFMA. Waves own strip sets
// {0,1},{2,3},{0,2,3},{1,2,3} (10 strip-reads/slot).
// =====================================================================
__global__ __launch_bounds__(256, 3)
void gram_ph(const float* __restrict__ x,
             const float* __restrict__ cent,
             float* __restrict__ Cp,
             float* __restrict__ normsq)
{
    __shared__ __align__(16) float fbuf[8192];   // 32 KB f32 k64 chunk
    __shared__ float Ssh[4][128];
    __shared__ float rmv[128];
    __shared__ float red[256];
    __shared__ float gmsh;

    const int tid = threadIdx.x, lane = tid & 63, wid = tid >> 6;
    const int n = blockIdx.x;
    const float* Amat = (n < BB) ? (x + (size_t)n * LL * HH)
                                 : (cent + (size_t)(n - BB) * LL * HH);

    const int lrow = lane >> 4;      // row within 4-row quad
    const int lu   = lane & 15;      // float4 unit within 256B row-chunk
    const int rbase = wid * 32 + lrow;

    f32x16 t0, t1, t2;
#pragma unroll
    for (int q = 0; q < 16; ++q) { t0[q] = 0.f; t1[q] = 0.f; t2[q] = 0.f; }

#pragma unroll 1
    for (int p = 0; p < 8; ++p) {
        // ---- issue 8 dense loads (4 rows x 256B each) ----
        float4 st[8];
#pragma unroll
        for (int i = 0; i < 8; ++i)
            st[i] = *(const float4*)(Amat + (size_t)(rbase + i * 4) * HH +
                                     p * 64 + lu * 4);
        __syncthreads();     // previous phase's LDS reads complete
#pragma unroll
        for (int i = 0; i < 8; ++i) {
            const int r = rbase + i * 4;
            *(float4*)((char*)fbuf + (r * 256 + ((lu * 16) ^ ((r & 7) << 4)))) = st[i];
        }
        __syncthreads();     // staged chunk visible
        // ---- MFMA over 4 k16-slots ----
        switch (wid) {
            case 0:  mfma_phase<2,3, 0,1,0, 0,0, 0,1, 1,1>(fbuf, lane, t0, t1, t2); break;
            case 1:  mfma_phase<2,3, 2,3,0, 0,0, 0,1, 1,1>(fbuf, lane, t0, t1, t2); break;
            case 2:  mfma_phase<3,2, 0,2,3, 0,1, 0,2, 0,0>(fbuf, lane, t0, t1, t2); break;
            default: mfma_phase<3,2, 1,2,3, 0,1, 0,2, 0,0>(fbuf, lane, t0, t1, t2); break;
        }
    }

    // ---- raw-Gram row sums for double-centering ----
    Ssh[wid][lane] = 0.f;
    Ssh[wid][lane + 64] = 0.f;
    if (wid == 0) {
        tile_sums(t0, Ssh[0], 0, 0, false, lane);
        tile_sums(t1, Ssh[0], 0, 1, true,  lane);
        tile_sums(t2, Ssh[0], 1, 1, false, lane);
    } else if (wid == 1) {
        tile_sums(t0, Ssh[1], 2, 2, false, lane);
        tile_sums(t1, Ssh[1], 2, 3, true,  lane);
        tile_sums(t2, Ssh[1], 3, 3, false, lane);
    } else if (wid == 2) {
        tile_sums(t0, Ssh[2], 0, 2, true, lane);
        tile_sums(t1, Ssh[2], 0, 3, true, lane);
    } else {
        tile_sums(t0, Ssh[3], 1, 2, true, lane);
        tile_sums(t1, Ssh[3], 1, 3, true, lane);
    }
    __syncthreads();

    float Sv = 0.f;
    if (tid < 128) {
        Sv = Ssh[0][tid] + Ssh[1][tid] + Ssh[2][tid] + Ssh[3][tid];
        rmv[tid] = Sv * (1.f / 128.f);
    }
    red[tid] = (tid < 128) ? Sv : 0.f;
    __syncthreads();
    for (int s2 = 128; s2 > 0; s2 >>= 1) {
        if (tid < s2) red[tid] += red[tid + s2];
        __syncthreads();
    }
    if (tid == 0) gmsh = red[0] * (1.f / 16384.f);
    __syncthreads();
    const float gm = gmsh;

    // ---- center + sqrt2-scale + store; ||C||^2 ----
    float nsq = 0.f;
    float* dst = Cp + (size_t)n * CPLEN;
    if (wid == 0) {
        nsq += tile_fin(t0, rmv, gm, false, 0, 0, dst + 0 * 1024, lane);
        nsq += tile_fin(t1, rmv, gm, true,  0, 1, dst + 1 * 1024, lane);
        nsq += tile_fin(t2, rmv, gm, false, 1, 1, dst + 4 * 1024, lane);
    } else if (wid == 1) {
        nsq += tile_fin(t0, rmv, gm, false, 2, 2, dst + 7 * 1024, lane);
        nsq += tile_fin(t1, rmv, gm, true,  2, 3, dst + 8 * 1024, lane);
        nsq += tile_fin(t2, rmv, gm, false, 3, 3, dst + 9 * 1024, lane);
    } else if (wid == 2) {
        nsq += tile_fin(t0, rmv, gm, true, 0, 2, dst + 2 * 1024, lane);
        nsq += tile_fin(t1, rmv, gm, true, 0, 3, dst + 3 * 1024, lane);
    } else {
        nsq += tile_fin(t0, rmv, gm, true, 1, 2, dst + 5 * 1024, lane);
        nsq += tile_fin(t1, rmv, gm, true, 1, 3, dst + 6 * 1024, lane);
    }
    __syncthreads();
    red[tid] = nsq;
    __syncthreads();
    for (int s2 = 128; s2 > 0; s2 >>= 1) {
        if (tid < s2) red[tid] += red[tid + s2];
        __syncthreads();
    }
    if (tid == 0) normsq[n] = red[0];
}

// =====================================================================
// K2: hsic partials. grid = 16 m-tiles x 40 k-chunks (640 blocks).
// =====================================================================
__global__ __launch_bounds__(256, 2)
void hsic_partial(const float* __restrict__ Cp, float* __restrict__ part)
{
    __shared__ float cx[32][260];
    __shared__ float red2[256][16];

    const int tid = threadIdx.x;
    const int bx  = blockIdx.x;
    const int mt  = bx / NCH;
    const int kc  = bx % NCH;
    const int k0  = kc * 256;

#pragma unroll
    for (int i = 0; i < 8; ++i) {
        const int idx = i * 1024 + tid * 4;
        const int b = idx >> 8, k = idx & 255;
        *(float4*)&cx[b][k] = *(const float4*)&Cp[(size_t)b * CPLEN + k0 + k];
    }
    __syncthreads();

    const int kq = tid >> 6;
    const int bg = (tid >> 3) & 7;
    const int mg = tid & 7;
    const float* cyBase = Cp + (size_t)(BB + mt * 32 + mg * 4) * CPLEN + k0 + kq * 64;

    float a[4][4];
#pragma unroll
    for (int bi = 0; bi < 4; ++bi)
#pragma unroll
        for (int mi = 0; mi < 4; ++mi) a[bi][mi] = 0.f;

    for (int kk = 0; kk < 16; ++kk) {
        float4 cy[4];
#pragma unroll
        for (int mi = 0; mi < 4; ++mi)
            cy[mi] = *(const float4*)(cyBase + (size_t)mi * CPLEN + kk * 4);
        float4 cxv[4];
#pragma unroll
        for (int bi = 0; bi < 4; ++bi)
            cxv[bi] = *(const float4*)&cx[bg + bi * 8][kq * 64 + kk * 4];
#pragma unroll
        for (int bi = 0; bi < 4; ++bi)
#pragma unroll
            for (int mi = 0; mi < 4; ++mi) {
                a[bi][mi] = fmaf(cxv[bi].x, cy[mi].x, a[bi][mi]);
                a[bi][mi] = fmaf(cxv[bi].y, cy[mi].y, a[bi][mi]);
                a[bi][mi] = fmaf(cxv[bi].z, cy[mi].z, a[bi][mi]);
                a[bi][mi] = fmaf(cxv[bi].w, cy[mi].w, a[bi][mi]);
            }
    }

#pragma unroll
    for (int e = 0; e < 16; ++e) red2[tid][e] = a[e >> 2][e & 3];
    __syncthreads();
    if (tid < 64) {
#pragma unroll
        for (int e = 0; e < 16; ++e) {
            const float s = red2[tid][e] + red2[tid + 64][e] +
                            red2[tid + 128][e] + red2[tid + 192][e];
            const int bi = e >> 2, mi = e & 3;
            const int b = ((tid >> 3) & 7) + bi * 8;
            const int m = mt * 32 + (tid & 7) * 4 + mi;
            part[((size_t)kc * 32 + b) * 512 + m] = s;
        }
    }
}

// =====================================================================
// K3: combine partials, loss matrix + per-row argmax (first occurrence)
// =====================================================================
__global__ __launch_bounds__(256)
void combine_loss(const float* __restrict__ part,
                  const float* __restrict__ normsq,
                  float* __restrict__ hsic,
                  int* __restrict__ ids,
                  float* __restrict__ out)
{
    __shared__ float rv[256];
    __shared__ int   ri[256];
    const int b = blockIdx.x;
    const int tid = threadIdx.x;
    const float vx = sqrtf(normsq[b]);

    float best = -INFINITY; int bm = 0;
    for (int m = tid; m < MM; m += 256) {
        float s = 0.f;
        for (int kc = 0; kc < NCH; ++kc)
            s += part[((size_t)kc * 32 + b) * 512 + m];
        hsic[b * MM + m] = s;
        const float vy = sqrtf(normsq[BB + m]);
        const float loss = -logf(fabsf(s) / (vx * vy) + EPSF);
        out[1 + b * MM + m] = loss;
        if (loss > best) { best = loss; bm = m; }   // ascending m keeps earliest
    }
    rv[tid] = best; ri[tid] = bm;
    __syncthreads();
    for (int s2 = 128; s2 > 0; s2 >>= 1) {
        if (tid < s2) {
            if (rv[tid + s2] > rv[tid] ||
                (rv[tid + s2] == rv[tid] && ri[tid + s2] < ri[tid])) {
                rv[tid] = rv[tid + s2]; ri[tid] = ri[tid + s2];
            }
        }
        __syncthreads();
    }
    if (tid == 0) { ids[b] = ri[0]; out[1 + BB * MM + b] = (float)ri[0]; }
}

// =====================================================================
// K4: scalar loss via gather identity hsic2[b,c] = hsic[b, idx[c]]
// =====================================================================
__global__ __launch_bounds__(1024)
void scalar_loss(const float* __restrict__ hsic,
                 const float* __restrict__ normsq,
                 const int* __restrict__ ids,
                 float* __restrict__ out)
{
    __shared__ float red[1024];
    const int tid = threadIdx.x;
    const int b = tid >> 5, c = tid & 31;
    const int m = ids[c];
    red[tid] = fabsf(hsic[b * MM + m]) /
               (sqrtf(normsq[b]) * sqrtf(normsq[BB + m]));
    __syncthreads();
    for (int s = 512; s > 0; s >>= 1) {
        if (tid < s) red[tid] += red[tid + s];
        __syncthreads();
    }
    if (tid == 0) out[0] = -logf(red[0] * (1.f / 1024.f) + EPSF);
}

// =====================================================================
extern "C" void kernel_launch(void* const* d_in, const int* in_sizes, int n_in,
                              void* d_out, int out_size, void* d_ws, size_t ws_size,
                              hipStream_t stream) {
    const float* x    = (const float*)d_in[0];   // (32,128,512)
    const float* cent = (const float*)d_in[1];   // (512, 128*512)
    float* out = (float*)d_out;
    float* ws  = (float*)d_ws;

    float* Cp     = ws + NWS_CP;
    float* part   = ws + NWS_PART;
    float* normsq = ws + NWS_NSQ;
    float* hsic   = ws + NWS_HSIC;
    int*   ids    = (int*)(ws + NWS_IDS);

    gram_ph<<<NM, 256, 0, stream>>>(x, cent, Cp, normsq);
    hsic_partial<<<16 * NCH, 256, 0, stream>>>(Cp, part);
    combine_loss<<<BB, 256, 0, stream>>>(part, normsq, hsic, ids, out);
    scalar_loss<<<1, 1024, 0, stream>>>(hsic, normsq, ids, out);
}

// Round 11
// 99.388 us; speedup vs baseline: 1.2334x; 1.1797x over previous
//
#include <hip/hip_runtime.h>
#include <math.h>

#define BB 32
#define LL 128
#define HH 512
#define MM 512
#define NM 544          // 32 x-matrices + 512 centroids
#define EPSF 1e-8f
#define CPLEN 10240     // 10 upper 32x32 tiles * 1024 floats (offdiag pre-scaled by sqrt2)
#define NCH 40          // k-chunks of 256 floats
#define R2C 1.41421356237309505f

typedef __attribute__((ext_vector_type(8))) short short8b;   // 8 bf16
typedef __attribute__((ext_vector_type(4))) float f32x4;
typedef __attribute__((ext_vector_type(16))) float f32x16;

// ---------------- ws layout (floats) ----------------
#define NWS_CP    0
#define NWS_PART  5570560
#define NWS_NSQ   6225920
#define NWS_HSIC  6226464
#define NWS_IDS   6242848

#define AS1(p) ((const __attribute__((address_space(1))) void*)(p))
#define AS3(p) ((__attribute__((address_space(3))) void*)(p))

__device__ __forceinline__ unsigned pack2(unsigned lo, unsigned hi) {
    return (lo >> 16) | (hi & 0xffff0000u);
}

// exact 3-plane bf16 split of 8 floats (c = p0+p1+p2 to ~2^-24 rel)
__device__ __forceinline__ void split3(const float4 lo, const float4 hi,
                                       uint4& p0, uint4& p1, uint4& p2) {
    float c[8] = {lo.x, lo.y, lo.z, lo.w, hi.x, hi.y, hi.z, hi.w};
    unsigned h[8], m[8], l[8];
#pragma unroll
    for (int i = 0; i < 8; ++i) {
        h[i] = __float_as_uint(c[i]) & 0xffff0000u;
        const float r1 = c[i] - __uint_as_float(h[i]);
        m[i] = __float_as_uint(r1) & 0xffff0000u;
        l[i] = __float_as_uint(r1 - __uint_as_float(m[i]));
    }
    p0 = make_uint4(pack2(h[0],h[1]), pack2(h[2],h[3]), pack2(h[4],h[5]), pack2(h[6],h[7]));
    p1 = make_uint4(pack2(m[0],m[1]), pack2(m[2],m[3]), pack2(m[4],m[5]), pack2(m[6],m[7]));
    p2 = make_uint4(pack2(l[0],l[1]), pack2(l[2],l[3]), pack2(l[4],l[5]), pack2(l[6],l[7]));
}

// 6 significant plane-products: hh, hm, mh, mm, hl, lh
__device__ __forceinline__ void mfma6(f32x16& d, const short8b a[3], const short8b b[3]) {
    d = __builtin_amdgcn_mfma_f32_32x32x16_bf16(a[0], b[0], d, 0, 0, 0);
    d = __builtin_amdgcn_mfma_f32_32x32x16_bf16(a[0], b[1], d, 0, 0, 0);
    d = __builtin_amdgcn_mfma_f32_32x32x16_bf16(a[1], b[0], d, 0, 0, 0);
    d = __builtin_amdgcn_mfma_f32_32x32x16_bf16(a[1], b[1], d, 0, 0, 0);
    d = __builtin_amdgcn_mfma_f32_32x32x16_bf16(a[0], b[2], d, 0, 0, 0);
    d = __builtin_amdgcn_mfma_f32_32x32x16_bf16(a[2], b[0], d, 0, 0, 0);
}

// row sums (-> strip i) and, for offdiag, col sums (-> strip j) of raw tile
// (verified 32x32 C/D layout: col=lane&31, row=(q&3)+8*(q>>2)+4*(lane>>5))
__device__ __forceinline__ void tile_sums(f32x16 a, float* S, int i, int j,
                                          bool offd, int lane) {
    const int hi = lane >> 5;
    float rs[16];
#pragma unroll
    for (int q = 0; q < 16; ++q) {
        float s = a[q];
        s += __shfl_xor(s, 1, 64);
        s += __shfl_xor(s, 2, 64);
        s += __shfl_xor(s, 4, 64);
        s += __shfl_xor(s, 8, 64);
        s += __shfl_xor(s, 16, 64);
        rs[q] = s;
    }
    if ((lane & 31) == 0) {
#pragma unroll
        for (int q = 0; q < 16; ++q)
            S[i * 32 + (q & 3) + 8 * (q >> 2) + 4 * hi] += rs[q];
    }
    if (offd) {
        float cs = 0.f;
#pragma unroll
        for (int q = 0; q < 16; ++q) cs += a[q];
        cs += __shfl_xor(cs, 32, 64);
        if (lane < 32) S[j * 32 + lane] += cs;
    }
}

// center + scale + store one tile; returns ||.||^2 partial
__device__ __forceinline__ float tile_fin(f32x16 a, const float* rmv, float gm,
                                          bool offd, int i, int j,
                                          float* dst, int lane) {
    const int hi = lane >> 5, col = lane & 31;
    const float cj = rmv[j * 32 + col];
    const float sc = offd ? R2C : 1.f;
    float nsq = 0.f;
#pragma unroll
    for (int c = 0; c < 4; ++c) {
        const float4 ri = *(const float4*)&rmv[i * 32 + c * 8 + hi * 4];
        const float riq[4] = {ri.x, ri.y, ri.z, ri.w};
        f32x4 o;
#pragma unroll
        for (int q = 0; q < 4; ++q) {
            float vq = (a[c * 4 + q] + gm - riq[q] - cj) * sc;
            nsq = fmaf(vq, vq, nsq);
            o[q] = vq;
        }
        *(f32x4*)(dst + (c * 2 + hi) * 128 + col * 4) = o;
    }
    return nsq;
}

// one k64-phase of MFMA work; reads XOR-swizzled f32 LDS, splits in regs
template<int NS, int NT, int S0, int S1, int S2,
         int A0, int B0, int A1, int B1, int A2, int B2>
__device__ __forceinline__ void mfma_phase(const float* fb, int lane,
                                           f32x16& t0, f32x16& t1, f32x16& t2)
{
    const int o = lane >> 5, r31 = lane & 31;
    const int SS[3] = {S0, S1, S2};
#pragma unroll
    for (int t = 0; t < 4; ++t) {
        short8b fr[3][3];
#pragma unroll
        for (int s = 0; s < NS; ++s) {
            const int r = SS[s] * 32 + r31;
            const int u = t * 4 + o * 2;
            const float4 lo = *(const float4*)&fb[r * 64 + ((u ^ (r & 15)) << 2)];
            const float4 hi = *(const float4*)&fb[r * 64 + (((u + 1) ^ (r & 15)) << 2)];
            uint4 q0, q1, q2;
            split3(lo, hi, q0, q1, q2);
            fr[s][0] = *(short8b*)&q0;
            fr[s][1] = *(short8b*)&q1;
            fr[s][2] = *(short8b*)&q2;
        }
        mfma6(t0, fr[A0], fr[B0]);
        if (NT > 1) mfma6(t1, fr[A1], fr[B1]);
        if (NT > 2) mfma6(t2, fr[A2], fr[B2]);
    }
}

// =====================================================================
// K1: async-DMA centered Gram. 544 blocks x 256 threads, 2 blocks/CU.
// Per k64 phase: 8 global_load_lds dwordx4 per wave (rows wid*32..+31,
// source chunk pre-swizzled c^(r&15), LDS dest linear), counted
// s_waitcnt vmcnt(8) so next-phase loads stay in flight across both
// barriers. Read+split3+MFMA per phase. Epilogue = R10's verified path.
// =====================================================================
__global__ __launch_bounds__(256, 2)
void gram_async(const float* __restrict__ x,
                const float* __restrict__ cent,
                float* __restrict__ Cp,
                float* __restrict__ normsq)
{
    __shared__ __align__(16) float fbuf[2][8192];   // 2 x 32 KB k64 chunks
    __shared__ float Ssh[4][128];
    __shared__ float rmv[128];
    __shared__ float red[256];
    __shared__ float gmsh;

    const int tid = threadIdx.x, lane = tid & 63, wid = tid >> 6;
    const int n = blockIdx.x;
    const float* Amat = (n < BB) ? (x + (size_t)n * LL * HH)
                                 : (cent + (size_t)(n - BB) * LL * HH);

    const int lrow = lane >> 4;      // row within 4-row group
    const int lc   = lane & 15;      // float4 chunk within 256B row-segment

    f32x16 t0, t1, t2;
#pragma unroll
    for (int q = 0; q < 16; ++q) { t0[q] = 0.f; t1[q] = 0.f; t2[q] = 0.f; }

    // per-lane source bases for the wave's 8 DMA instructions (pre-swizzled)
    const float* srcb[8];
#pragma unroll
    for (int i = 0; i < 8; ++i) {
        const int r = wid * 32 + i * 4 + lrow;
        srcb[i] = Amat + (size_t)r * HH + ((lc ^ (r & 15)) << 2);
    }

    // prologue: stage phase 0 into buf0
#pragma unroll
    for (int i = 0; i < 8; ++i)
        __builtin_amdgcn_global_load_lds(AS1(srcb[i]),
            AS3(&fbuf[0][(wid * 32 + i * 4) * 64]), 16, 0, 0);

#pragma unroll 1
    for (int p = 0; p < 8; ++p) {
        const float* fbCur = fbuf[p & 1];
        float* fbNxt = fbuf[(p + 1) & 1];
        if (p < 7) {
            // issue stage(p+1): safe, all waves finished reading this buffer
            // at the barrier ending phase p-1
#pragma unroll
            for (int i = 0; i < 8; ++i)
                __builtin_amdgcn_global_load_lds(AS1(srcb[i] + (p + 1) * 64),
                    AS3(&fbNxt[(wid * 32 + i * 4) * 64]), 16, 0, 0);
            asm volatile("s_waitcnt vmcnt(8)" ::: "memory");   // stage(p) done
        } else {
            asm volatile("s_waitcnt vmcnt(0)" ::: "memory");
        }
        __builtin_amdgcn_s_barrier();          // buf[p] fully staged, all waves
        __builtin_amdgcn_sched_barrier(0);
        switch (wid) {
            case 0:  mfma_phase<2,3, 0,1,0, 0,0, 0,1, 1,1>(fbCur, lane, t0, t1, t2); break;
            case 1:  mfma_phase<2,3, 2,3,0, 0,0, 0,1, 1,1>(fbCur, lane, t0, t1, t2); break;
            case 2:  mfma_phase<3,2, 0,2,3, 0,1, 0,2, 0,0>(fbCur, lane, t0, t1, t2); break;
            default: mfma_phase<3,2, 1,2,3, 0,1, 0,2, 0,0>(fbCur, lane, t0, t1, t2); break;
        }
        __builtin_amdgcn_s_barrier();          // all reads of buf[p] done
    }

    // ---- raw-Gram row sums for double-centering ----
    Ssh[wid][lane] = 0.f;
    Ssh[wid][lane + 64] = 0.f;
    if (wid == 0) {
        tile_sums(t0, Ssh[0], 0, 0, false, lane);
        tile_sums(t1, Ssh[0], 0, 1, true,  lane);
        tile_sums(t2, Ssh[0], 1, 1, false, lane);
    } else if (wid == 1) {
        tile_sums(t0, Ssh[1], 2, 2, false, lane);
        tile_sums(t1, Ssh[1], 2, 3, true,  lane);
        tile_sums(t2, Ssh[1], 3, 3, false, lane);
    } else if (wid == 2) {
        tile_sums(t0, Ssh[2], 0, 2, true, lane);
        tile_sums(t1, Ssh[2], 0, 3, true, lane);
    } else {
        tile_sums(t0, Ssh[3], 1, 2, true, lane);
        tile_sums(t1, Ssh[3], 1, 3, true, lane);
    }
    __syncthreads();

    float Sv = 0.f;
    if (tid < 128) {
        Sv = Ssh[0][tid] + Ssh[1][tid] + Ssh[2][tid] + Ssh[3][tid];
        rmv[tid] = Sv * (1.f / 128.f);
    }
    red[tid] = (tid < 128) ? Sv : 0.f;
    __syncthreads();
    for (int s2 = 128; s2 > 0; s2 >>= 1) {
        if (tid < s2) red[tid] += red[tid + s2];
        __syncthreads();
    }
    if (tid == 0) gmsh = red[0] * (1.f / 16384.f);
    __syncthreads();
    const float gm = gmsh;

    // ---- center + sqrt2-scale + store; ||C||^2 ----
    float nsq = 0.f;
    float* dst = Cp + (size_t)n * CPLEN;
    if (wid == 0) {
        nsq += tile_fin(t0, rmv, gm, false, 0, 0, dst + 0 * 1024, lane);
        nsq += tile_fin(t1, rmv, gm, true,  0, 1, dst + 1 * 1024, lane);
        nsq += tile_fin(t2, rmv, gm, false, 1, 1, dst + 4 * 1024, lane);
    } else if (wid == 1) {
        nsq += tile_fin(t0, rmv, gm, false, 2, 2, dst + 7 * 1024, lane);
        nsq += tile_fin(t1, rmv, gm, true,  2, 3, dst + 8 * 1024, lane);
        nsq += tile_fin(t2, rmv, gm, false, 3, 3, dst + 9 * 1024, lane);
    } else if (wid == 2) {
        nsq += tile_fin(t0, rmv, gm, true, 0, 2, dst + 2 * 1024, lane);
        nsq += tile_fin(t1, rmv, gm, true, 0, 3, dst + 3 * 1024, lane);
    } else {
        nsq += tile_fin(t0, rmv, gm, true, 1, 2, dst + 5 * 1024, lane);
        nsq += tile_fin(t1, rmv, gm, true, 1, 3, dst + 6 * 1024, lane);
    }
    __syncthreads();
    red[tid] = nsq;
    __syncthreads();
    for (int s2 = 128; s2 > 0; s2 >>= 1) {
        if (tid < s2) red[tid] += red[tid + s2];
        __syncthreads();
    }
    if (tid == 0) normsq[n] = red[0];
}

// =====================================================================
// K2: hsic partials. grid = 16 m-tiles x 40 k-chunks (640 blocks).
// =====================================================================
__global__ __launch_bounds__(256, 2)
void hsic_partial(const float* __restrict__ Cp, float* __restrict__ part)
{
    __shared__ float cx[32][260];
    __shared__ float red2[256][16];

    const int tid = threadIdx.x;
    const int bx  = blockIdx.x;
    const int mt  = bx / NCH;
    const int kc  = bx % NCH;
    const int k0  = kc * 256;

#pragma unroll
    for (int i = 0; i < 8; ++i) {
        const int idx = i * 1024 + tid * 4;
        const int b = idx >> 8, k = idx & 255;
        *(float4*)&cx[b][k] = *(const float4*)&Cp[(size_t)b * CPLEN + k0 + k];
    }
    __syncthreads();

    const int kq = tid >> 6;
    const int bg = (tid >> 3) & 7;
    const int mg = tid & 7;
    const float* cyBase = Cp + (size_t)(BB + mt * 32 + mg * 4) * CPLEN + k0 + kq * 64;

    float a[4][4];
#pragma unroll
    for (int bi = 0; bi < 4; ++bi)
#pragma unroll
        for (int mi = 0; mi < 4; ++mi) a[bi][mi] = 0.f;

    for (int kk = 0; kk < 16; ++kk) {
        float4 cy[4];
#pragma unroll
        for (int mi = 0; mi < 4; ++mi)
            cy[mi] = *(const float4*)(cyBase + (size_t)mi * CPLEN + kk * 4);
        float4 cxv[4];
#pragma unroll
        for (int bi = 0; bi < 4; ++bi)
            cxv[bi] = *(const float4*)&cx[bg + bi * 8][kq * 64 + kk * 4];
#pragma unroll
        for (int bi = 0; bi < 4; ++bi)
#pragma unroll
            for (int mi = 0; mi < 4; ++mi) {
                a[bi][mi] = fmaf(cxv[bi].x, cy[mi].x, a[bi][mi]);
                a[bi][mi] = fmaf(cxv[bi].y, cy[mi].y, a[bi][mi]);
                a[bi][mi] = fmaf(cxv[bi].z, cy[mi].z, a[bi][mi]);
                a[bi][mi] = fmaf(cxv[bi].w, cy[mi].w, a[bi][mi]);
            }
    }

#pragma unroll
    for (int e = 0; e < 16; ++e) red2[tid][e] = a[e >> 2][e & 3];
    __syncthreads();
    if (tid < 64) {
#pragma unroll
        for (int e = 0; e < 16; ++e) {
            const float s = red2[tid][e] + red2[tid + 64][e] +
                            red2[tid + 128][e] + red2[tid + 192][e];
            const int bi = e >> 2, mi = e & 3;
            const int b = ((tid >> 3) & 7) + bi * 8;
            const int m = mt * 32 + (tid & 7) * 4 + mi;
            part[((size_t)kc * 32 + b) * 512 + m] = s;
        }
    }
}

// =====================================================================
// K3: combine partials, loss matrix + per-row argmax (first occurrence)
// =====================================================================
__global__ __launch_bounds__(256)
void combine_loss(const float* __restrict__ part,
                  const float* __restrict__ normsq,
                  float* __restrict__ hsic,
                  int* __restrict__ ids,
                  float* __restrict__ out)
{
    __shared__ float rv[256];
    __shared__ int   ri[256];
    const int b = blockIdx.x;
    const int tid = threadIdx.x;
    const float vx = sqrtf(normsq[b]);

    float best = -INFINITY; int bm = 0;
    for (int m = tid; m < MM; m += 256) {
        float s = 0.f;
        for (int kc = 0; kc < NCH; ++kc)
            s += part[((size_t)kc * 32 + b) * 512 + m];
        hsic[b * MM + m] = s;
        const float vy = sqrtf(normsq[BB + m]);
        const float loss = -logf(fabsf(s) / (vx * vy) + EPSF);
        out[1 + b * MM + m] = loss;
        if (loss > best) { best = loss; bm = m; }   // ascending m keeps earliest
    }
    rv[tid] = best; ri[tid] = bm;
    __syncthreads();
    for (int s2 = 128; s2 > 0; s2 >>= 1) {
        if (tid < s2) {
            if (rv[tid + s2] > rv[tid] ||
                (rv[tid + s2] == rv[tid] && ri[tid + s2] < ri[tid])) {
                rv[tid] = rv[tid + s2]; ri[tid] = ri[tid + s2];
            }
        }
        __syncthreads();
    }
    if (tid == 0) { ids[b] = ri[0]; out[1 + BB * MM + b] = (float)ri[0]; }
}

// =====================================================================
// K4: scalar loss via gather identity hsic2[b,c] = hsic[b, idx[c]]
// =====================================================================
__global__ __launch_bounds__(1024)
void scalar_loss(const float* __restrict__ hsic,
                 const float* __restrict__ normsq,
                 const int* __restrict__ ids,
                 float* __restrict__ out)
{
    __shared__ float red[1024];
    const int tid = threadIdx.x;
    const int b = tid >> 5, c = tid & 31;
    const int m = ids[c];
    red[tid] = fabsf(hsic[b * MM + m]) /
               (sqrtf(normsq[b]) * sqrtf(normsq[BB + m]));
    __syncthreads();
    for (int s = 512; s > 0; s >>= 1) {
        if (tid < s) red[tid] += red[tid + s];
        __syncthreads();
    }
    if (tid == 0) out[0] = -logf(red[0] * (1.f / 1024.f) + EPSF);
}

// =====================================================================
extern "C" void kernel_launch(void* const* d_in, const int* in_sizes, int n_in,
                              void* d_out, int out_size, void* d_ws, size_t ws_size,
                              hipStream_t stream) {
    const float* x    = (const float*)d_in[0];   // (32,128,512)
    const float* cent = (const float*)d_in[1];   // (512, 128*512)
    float* out = (float*)d_out;
    float* ws  = (float*)d_ws;

    float* Cp     = ws + NWS_CP;
    float* part   = ws + NWS_PART;
    float* normsq = ws + NWS_NSQ;
    float* hsic   = ws + NWS_HSIC;
    int*   ids    = (int*)(ws + NWS_IDS);

    gram_async<<<NM, 256, 0, stream>>>(x, cent, Cp, normsq);
    hsic_partial<<<16 * NCH, 256, 0, stream>>>(Cp, part);
    combine_loss<<<BB, 256, 0, stream>>>(part, normsq, hsic, ids, out);
    scalar_loss<<<1, 1024, 0, stream>>>(hsic, normsq, ids, out);
}